// Round 7
// baseline (642.615 us; speedup 1.0000x reference)
//
#include <hip/hip_runtime.h>
#include <cfloat>
#include <cmath>

// GAT layer: B=4,S=256,N=257,E=256, IN=OUT=128, EDIM=16, all f32.
// R6 fix: W-tile LDS staging copied 8 ushorts instead of 16 (uint4 is 16 B,
// not 32 B) -> half of B fragments were uninitialized LDS -> NaN. Now copies
// two uint4 per thread.
// Phases:
//   K0 detect+canon: edge_mask dtype sniffing (int32 vs uint8) -> uint8 in ws
//   Kp wprep: W f32 -> transposed bf16 hi/lo (Wt[n][k]) in ws
//   K1 mfma_gemm: h = x @ W via 3-term bf16 MFMA; epilogue pq/pt dots
//   K2 alpha2: per-(b,s) edge logits from pq/pt + masked softmax -> ws
//   K3 agg512: per-(b,s, D/8) LDS-staged scatter-accumulate + ELU -> d_out
// Index semantics replicate JAX: gather for logits zeroes idx<0; aggregation
// uses where(mask, idx, 0) then NEGATIVE WRAP (-1 -> 256).

#define BB 4
#define SS 256
#define NNODE 257
#define EE 256
#define DIN 128
#define DOUT 128
#define EDIMC 16
#define NMASK (BB * SS * EE)          // 262144
#define MROWS (BB * SS * NNODE)       // 263168

// ws layout (bytes):
#define WS_FLAG_OFF  0
#define WS_MASK_OFF  1024
#define WS_ALPHA_OFF 266240                        // + NMASK*4
#define WS_PQ_OFF    (WS_ALPHA_OFF + NMASK * 4)    // + MROWS*4
#define WS_PT_OFF    (WS_PQ_OFF + MROWS * 4)       // + MROWS*4
#define WS_WTHI_OFF  (WS_PT_OFF + MROWS * 4)       // + 128*128*2
#define WS_WTLO_OFF  (WS_WTHI_OFF + DIN * DOUT * 2)
#define WS_NEEDED    (WS_WTLO_OFF + DIN * DOUT * 2)   // ~3.5 MB

typedef __attribute__((ext_vector_type(8))) short bf16x8;
typedef __attribute__((ext_vector_type(4))) float f32x4;

__device__ __forceinline__ unsigned short f2bf(float f) {
    unsigned u = __float_as_uint(f);
    u += 0x7fff + ((u >> 16) & 1);           // RNE
    return (unsigned short)(u >> 16);
}
__device__ __forceinline__ float bf2f(unsigned short h) {
    return __uint_as_float((unsigned)h << 16);
}

// ------------------------------------------------------- mask dtype sniffing
__global__ void detect_mask_kernel(const unsigned int* __restrict__ m, int* flag) {
    unsigned int v = 0;
    for (int i = threadIdx.x; i < 256; i += 64) v |= m[i];
    int bad = (v > 1u) ? 1 : 0;
    bad = __any(bad) ? 1 : 0;
    if (threadIdx.x == 0) *flag = bad;
}

__global__ __launch_bounds__(256) void mask_canon_kernel(
        const int* __restrict__ m32, const unsigned char* __restrict__ m8,
        const int* __restrict__ flag, unsigned char* __restrict__ out) {
    const bool byteLayout = (*flag != 0);
    int i = blockIdx.x * 256 + threadIdx.x;
    if (i < NMASK) out[i] = byteLayout ? (m8[i] != 0) : (m32[i] != 0);
}

// ------------------------------------------------------- W prep (bf16 split)
// Wt_hi[n][k], Wt_lo[n][k] (transposed) from W[k][n] f32.
__global__ __launch_bounds__(256) void wprep_kernel(
        const float* __restrict__ W, unsigned short* __restrict__ wthi,
        unsigned short* __restrict__ wtlo) {
    const int tid = threadIdx.x;
    for (int i = tid; i < DIN * DOUT; i += 256) {
        const int k = i >> 7, n = i & 127;
        const float w = W[i];
        const unsigned short hi = f2bf(w);
        const unsigned short lo = f2bf(w - bf2f(hi));
        wthi[n * DIN + k] = hi;
        wtlo[n * DIN + k] = lo;
    }
}

// ---------------------------------------------------------------- MFMA GEMM
// h[M,128] = x[M,128] @ W[128,128] via bf16x3 split (xh*Wh + xh*Wl + xl*Wh).
// Block: 128 rows, 4 waves (2x2 wave grid of 64x64), BK=32, 4 K-tiles.
// Epilogue: pq = h . a[0:128], pt = h . a[128:256] reduced from acc frags.
#define XPAD 40   // ushort row stride (80 B: 16B-aligned, 2-way banks max)
__global__ __launch_bounds__(256) void mfma_gemm_kernel(
        const float* __restrict__ x, const unsigned short* __restrict__ wthi,
        const unsigned short* __restrict__ wtlo, const float* __restrict__ a,
        float* __restrict__ h, float* __restrict__ pq, float* __restrict__ pt) {
    __shared__ unsigned short xhi[128][XPAD];
    __shared__ unsigned short xlo[128][XPAD];
    __shared__ unsigned short bhi[128][XPAD];
    __shared__ unsigned short blo[128][XPAD];
    __shared__ float pqs[128], pts[128];

    const int tid = threadIdx.x;
    const long m0 = (long)blockIdx.x * 128;
    const int wave = tid >> 6, lane = tid & 63;
    const int wm = wave >> 1, wn = wave & 1;     // 2x2 wave grid of 64x64
    const int lrow = lane & 15;
    const int lk8 = (lane >> 4) * 8;             // k-offset of frag slice

    if (tid < 128) { pqs[tid] = 0.f; pts[tid] = 0.f; }

    f32x4 acc[4][4];
#pragma unroll
    for (int i = 0; i < 4; ++i)
#pragma unroll
        for (int j = 0; j < 4; ++j) acc[i][j] = (f32x4){0.f, 0.f, 0.f, 0.f};

    const int srow = tid >> 1;                   // staging: row per thread pair
    const int sk = (tid & 1) * 16;               // 16 consecutive k

    for (int kt = 0; kt < 4; ++kt) {
        __syncthreads();
        // ---- stage x tile (f32 -> bf16 hi/lo in LDS): 16 ushorts/thread
        {
            const float* src = x + (m0 + srow) * DIN + kt * 32 + sk;
#pragma unroll
            for (int q = 0; q < 4; ++q) {
                float4 v = *reinterpret_cast<const float4*>(src + q * 4);
                ushort4 hi, lo;
                hi.x = f2bf(v.x); lo.x = f2bf(v.x - bf2f(hi.x));
                hi.y = f2bf(v.y); lo.y = f2bf(v.y - bf2f(hi.y));
                hi.z = f2bf(v.z); lo.z = f2bf(v.z - bf2f(hi.z));
                hi.w = f2bf(v.w); lo.w = f2bf(v.w - bf2f(hi.w));
                *reinterpret_cast<ushort4*>(&xhi[srow][sk + q * 4]) = hi;
                *reinterpret_cast<ushort4*>(&xlo[srow][sk + q * 4]) = lo;
            }
        }
        // ---- stage Wt tiles (bf16, pre-transposed): 16 ushorts = 2x uint4
        {
            const int n = tid >> 1;
            const int kh = (tid & 1) * 16;
            const unsigned short* sh = wthi + n * DIN + kt * 32 + kh;
            const unsigned short* sl = wtlo + n * DIN + kt * 32 + kh;
            *reinterpret_cast<uint4*>(&bhi[n][kh]) =
                *reinterpret_cast<const uint4*>(sh);
            *reinterpret_cast<uint4*>(&bhi[n][kh + 8]) =
                *reinterpret_cast<const uint4*>(sh + 8);
            *reinterpret_cast<uint4*>(&blo[n][kh]) =
                *reinterpret_cast<const uint4*>(sl);
            *reinterpret_cast<uint4*>(&blo[n][kh + 8]) =
                *reinterpret_cast<const uint4*>(sl + 8);
        }
        __syncthreads();

        // ---- fragments + MFMA
        bf16x8 Bh[4], Bl[4];
#pragma unroll
        for (int fn = 0; fn < 4; ++fn) {
            const int n = wn * 64 + fn * 16 + lrow;
            Bh[fn] = *reinterpret_cast<const bf16x8*>(&bhi[n][lk8]);
            Bl[fn] = *reinterpret_cast<const bf16x8*>(&blo[n][lk8]);
        }
#pragma unroll
        for (int fm = 0; fm < 4; ++fm) {
            const int r = wm * 64 + fm * 16 + lrow;
            bf16x8 Ah = *reinterpret_cast<const bf16x8*>(&xhi[r][lk8]);
            bf16x8 Al = *reinterpret_cast<const bf16x8*>(&xlo[r][lk8]);
#pragma unroll
            for (int fn = 0; fn < 4; ++fn)
                acc[fm][fn] = __builtin_amdgcn_mfma_f32_16x16x32_bf16(
                    Ah, Bh[fn], acc[fm][fn], 0, 0, 0);
#pragma unroll
            for (int fn = 0; fn < 4; ++fn)
                acc[fm][fn] = __builtin_amdgcn_mfma_f32_16x16x32_bf16(
                    Ah, Bl[fn], acc[fm][fn], 0, 0, 0);
#pragma unroll
            for (int fn = 0; fn < 4; ++fn)
                acc[fm][fn] = __builtin_amdgcn_mfma_f32_16x16x32_bf16(
                    Al, Bh[fn], acc[fm][fn], 0, 0, 0);
        }
    }

    // ---- write h (C/D layout: col = lane&15, row = (lane>>4)*4 + reg)
    const int qrow = (lane >> 4) * 4;
    const int ccol = lane & 15;
#pragma unroll
    for (int fm = 0; fm < 4; ++fm) {
#pragma unroll
        for (int fn = 0; fn < 4; ++fn) {
            float* dst = h + (m0 + wm * 64 + fm * 16 + qrow) * DOUT +
                         wn * 64 + fn * 16 + ccol;
#pragma unroll
            for (int r = 0; r < 4; ++r) dst[(long)r * DOUT] = acc[fm][fn][r];
        }
    }

    // ---- pq/pt epilogue
    if (pq != nullptr) {
        float aq[4], at_[4];
#pragma unroll
        for (int fn = 0; fn < 4; ++fn) {
            aq[fn]  = a[wn * 64 + fn * 16 + ccol];
            at_[fn] = a[DOUT + wn * 64 + fn * 16 + ccol];
        }
#pragma unroll
        for (int fm = 0; fm < 4; ++fm) {
#pragma unroll
            for (int r = 0; r < 4; ++r) {
                float s = 0.f, t = 0.f;
#pragma unroll
                for (int fn = 0; fn < 4; ++fn) {
                    s = fmaf(acc[fm][fn][r], aq[fn], s);
                    t = fmaf(acc[fm][fn][r], at_[fn], t);
                }
#pragma unroll
                for (int o = 1; o < 16; o <<= 1) {
                    s += __shfl_xor(s, o);
                    t += __shfl_xor(t, o);
                }
                if (ccol == 0) {
                    atomicAdd(&pqs[wm * 64 + fm * 16 + qrow + r], s);
                    atomicAdd(&pts[wm * 64 + fm * 16 + qrow + r], t);
                }
            }
        }
        __syncthreads();
        if (tid < 128) {
            pq[m0 + tid] = pqs[tid];
            pt[m0 + tid] = pts[tid];
        }
    }
}

// ---------------------------------------- fallback f32 GEMM (ws too small)
__global__ __launch_bounds__(256) void gemm_kernel(const float* __restrict__ x,
                                                   const float* __restrict__ W,
                                                   float* __restrict__ h) {
    __shared__ float xs[32][132];
    __shared__ float wsh[32][132];
    const int tid = threadIdx.x;
    const long m0 = (long)blockIdx.x * 128;
    const int tm = tid >> 4, tn = tid & 15;
    const int mr = tm * 8, nr = tn * 8;
    float acc[8][8];
#pragma unroll
    for (int i = 0; i < 8; ++i)
#pragma unroll
        for (int j = 0; j < 8; ++j) acc[i][j] = 0.f;
    for (int kt = 0; kt < 4; ++kt) {
#pragma unroll
        for (int j = 0; j < 4; ++j) {
            int idx = j * 256 + tid;
            int row = idx >> 3, kq = idx & 7;
            float4 v = *reinterpret_cast<const float4*>(
                x + (m0 + row) * DIN + kt * 32 + kq * 4);
            xs[kq * 4 + 0][row] = v.x; xs[kq * 4 + 1][row] = v.y;
            xs[kq * 4 + 2][row] = v.z; xs[kq * 4 + 3][row] = v.w;
        }
#pragma unroll
        for (int j = 0; j < 4; ++j) {
            int idx = j * 256 + tid;
            int row = idx >> 5, nq = idx & 31;
            float4 v = *reinterpret_cast<const float4*>(
                W + (kt * 32 + row) * DOUT + nq * 4);
            *reinterpret_cast<float4*>(&wsh[row][nq * 4]) = v;
        }
        __syncthreads();
#pragma unroll
        for (int k = 0; k < 32; ++k) {
            float4 a0 = *reinterpret_cast<const float4*>(&xs[k][mr]);
            float4 a1 = *reinterpret_cast<const float4*>(&xs[k][mr + 4]);
            float4 b0 = *reinterpret_cast<const float4*>(&wsh[k][nr]);
            float4 b1 = *reinterpret_cast<const float4*>(&wsh[k][nr + 4]);
            float av[8] = {a0.x, a0.y, a0.z, a0.w, a1.x, a1.y, a1.z, a1.w};
            float bv[8] = {b0.x, b0.y, b0.z, b0.w, b1.x, b1.y, b1.z, b1.w};
#pragma unroll
            for (int i = 0; i < 8; ++i)
#pragma unroll
                for (int jj = 0; jj < 8; ++jj)
                    acc[i][jj] = fmaf(av[i], bv[jj], acc[i][jj]);
        }
        __syncthreads();
    }
#pragma unroll
    for (int i = 0; i < 8; ++i) {
        float* dst = h + (m0 + mr + i) * DOUT + nr;
        *reinterpret_cast<float4*>(dst) =
            make_float4(acc[i][0], acc[i][1], acc[i][2], acc[i][3]);
        *reinterpret_cast<float4*>(dst + 4) =
            make_float4(acc[i][4], acc[i][5], acc[i][6], acc[i][7]);
    }
}

// ---------------------------------------------------------------- alpha2
__global__ __launch_bounds__(256) void alpha2_kernel(
        const float* __restrict__ pq, const float* __restrict__ pt,
        const int* __restrict__ eidx, const float* __restrict__ eattr,
        const unsigned char* __restrict__ emask, const float* __restrict__ a,
        float* __restrict__ alpha_out) {
    __shared__ float ae[EDIMC];
    __shared__ float red[4];
    __shared__ int redi[4];
    const int tid = threadIdx.x;
    const int bs = blockIdx.x;
    const int lane = tid & 63, wave = tid >> 6;
    if (tid < EDIMC) ae[tid] = a[2 * DOUT + tid];
    __syncthreads();

    const long ebase = (long)bs * EE + tid;
    const int si = eidx[2 * ebase];
    const int ti = eidx[2 * ebase + 1];
    const float4* ea4 = reinterpret_cast<const float4*>(eattr + ebase * EDIMC);
    float dea = 0.f;
#pragma unroll
    for (int j = 0; j < 4; ++j) {
        float4 u = ea4[j];
        dea += u.x * ae[4 * j] + u.y * ae[4 * j + 1] +
               u.z * ae[4 * j + 2] + u.w * ae[4 * j + 3];
    }
    const long nb = (long)bs * NNODE;
    float val = (si >= 0 ? pq[nb + si] : 0.f) + (ti >= 0 ? pt[nb + ti] : 0.f) + dea;
    val = val > 0.f ? val : 0.2f * val;
    const bool m = emask[ebase] != 0;

    float wm = m ? val : -FLT_MAX;
    int anyv = m ? 1 : 0;
#pragma unroll
    for (int o = 32; o > 0; o >>= 1) {
        wm = fmaxf(wm, __shfl_xor(wm, o));
        anyv |= __shfl_xor(anyv, o);
    }
    if (lane == 0) { red[wave] = wm; redi[wave] = anyv; }
    __syncthreads();
    const float gmax = fmaxf(fmaxf(red[0], red[1]), fmaxf(red[2], red[3]));
    const int ganyv = redi[0] | redi[1] | redi[2] | redi[3];
    float ex = m ? expf(val - gmax) : 0.f;
    float sm = ex;
#pragma unroll
    for (int o = 32; o > 0; o >>= 1) sm += __shfl_xor(sm, o);
    __syncthreads();
    if (lane == 0) red[wave] = sm;
    __syncthreads();
    const float gsum = red[0] + red[1] + red[2] + red[3];
    alpha_out[ebase] = ganyv ? ex / gsum : (1.0f / EE);
}

// ------------------------------------------- alpha (fallback, reads h)
__global__ __launch_bounds__(256) void alpha_kernel(
        const float* __restrict__ h, const int* __restrict__ eidx,
        const float* __restrict__ eattr, const unsigned char* __restrict__ emask,
        const float* __restrict__ a, float* __restrict__ alpha_out) {
    __shared__ float pq[NNODE], pt[NNODE];
    __shared__ float ae[EDIMC];
    __shared__ float red[4];
    __shared__ int redi[4];
    const int tid = threadIdx.x;
    const int bs = blockIdx.x;
    const int lane = tid & 63, wave = tid >> 6;
    if (tid < EDIMC) ae[tid] = a[2 * DOUT + tid];
    const float a0 = a[lane], a1 = a[lane + 64];
    const float a2 = a[128 + lane], a3 = a[192 + lane];
    const float* hb = h + (long)bs * NNODE * DIN;
    for (int n = wave; n < NNODE; n += 4) {
        const float* hr = hb + n * DIN;
        float v0 = hr[lane], v1 = hr[lane + 64];
        float s = v0 * a0 + v1 * a1;
        float t = v0 * a2 + v1 * a3;
#pragma unroll
        for (int o = 32; o > 0; o >>= 1) {
            s += __shfl_xor(s, o);
            t += __shfl_xor(t, o);
        }
        if (lane == 0) { pq[n] = s; pt[n] = t; }
    }
    __syncthreads();

    const long ebase = (long)bs * EE + tid;
    const int si = eidx[2 * ebase];
    const int ti = eidx[2 * ebase + 1];
    const float4* ea4 = reinterpret_cast<const float4*>(eattr + ebase * EDIMC);
    float dea = 0.f;
#pragma unroll
    for (int j = 0; j < 4; ++j) {
        float4 u = ea4[j];
        dea += u.x * ae[4 * j] + u.y * ae[4 * j + 1] +
               u.z * ae[4 * j + 2] + u.w * ae[4 * j + 3];
    }
    float val = (si >= 0 ? pq[si] : 0.f) + (ti >= 0 ? pt[ti] : 0.f) + dea;
    val = val > 0.f ? val : 0.2f * val;
    const bool m = emask[ebase] != 0;

    float wm = m ? val : -FLT_MAX;
    int anyv = m ? 1 : 0;
#pragma unroll
    for (int o = 32; o > 0; o >>= 1) {
        wm = fmaxf(wm, __shfl_xor(wm, o));
        anyv |= __shfl_xor(anyv, o);
    }
    if (lane == 0) { red[wave] = wm; redi[wave] = anyv; }
    __syncthreads();
    const float gmax = fmaxf(fmaxf(red[0], red[1]), fmaxf(red[2], red[3]));
    const int ganyv = redi[0] | redi[1] | redi[2] | redi[3];
    float ex = m ? expf(val - gmax) : 0.f;
    float sm = ex;
#pragma unroll
    for (int o = 32; o > 0; o >>= 1) sm += __shfl_xor(sm, o);
    __syncthreads();
    if (lane == 0) red[wave] = sm;
    __syncthreads();
    const float gsum = red[0] + red[1] + red[2] + red[3];
    alpha_out[ebase] = ganyv ? ex / gsum : (1.0f / EE);
}

// ---------------------------------------------------------------- aggregate
// grid (B*S, 8), 512 threads: one (b,s) and 16 feature dims per block.
// 37 KB LDS -> 4 blocks/CU -> 32 waves/CU (vs 16 at 256 threads).
#define DSL 16
#define PAD 17
__global__ __launch_bounds__(512) void agg_kernel(
        const float* __restrict__ h, const int* __restrict__ eidx,
        const unsigned char* __restrict__ emask, const float* __restrict__ alpha,
        float* __restrict__ out) {
    __shared__ float hs[NNODE * PAD];
    __shared__ float acc[NNODE * PAD];
    __shared__ float meta_a[EE];
    __shared__ int   meta_v[EE];
    const int tid = threadIdx.x;
    const int bs = blockIdx.x;
    const int dbase = blockIdx.y * DSL;
    const int slot = tid >> 4, d = tid & 15;   // 32 slots x 16 dims

    const float* hb = h + (long)bs * NNODE * DIN + dbase;

    for (int i = tid; i < NNODE * 4; i += 512) {
        int row = i >> 2, q = i & 3;
        float4 v = *reinterpret_cast<const float4*>(hb + (long)row * DIN + q * 4);
        float* dst = &hs[row * PAD + q * 4];
        dst[0] = v.x; dst[1] = v.y; dst[2] = v.z; dst[3] = v.w;
    }
    for (int i = tid; i < NNODE * PAD; i += 512) acc[i] = 0.f;
    if (tid < EE) {
        const long eb = (long)bs * EE + tid;
        const int si = eidx[2 * eb];
        const int ti = eidx[2 * eb + 1];
        const bool m = emask[eb] != 0;
        int vs = m ? si : 0; if (vs < 0) vs += NNODE;   // JAX negative wrap
        int vt = m ? ti : 0; if (vt < 0) vt += NNODE;
        meta_a[tid] = alpha[eb];
        meta_v[tid] = vs | (vt << 16);
    }
    __syncthreads();

    // LDS-only edge loop: 8 iterations, 32 edges x 16 lanes each
#pragma unroll 4
    for (int e0 = 0; e0 < EE; e0 += 32) {
        const int e = e0 + slot;
        const float al = meta_a[e];
        if (al != 0.f) {
            const int pv = meta_v[e];
            const int vs = pv & 0xffff, vt = pv >> 16;
            const float hsv = hs[vs * PAD + d];
            const float htv = hs[vt * PAD + d];
            atomicAdd(&acc[vt * PAD + d], al * hsv);
            atomicAdd(&acc[vs * PAD + d], al * htv);
        }
    }
    __syncthreads();

    float* ob = out + (long)bs * NNODE * DIN + dbase;
    for (int n = slot; n < NNODE; n += 32) {
        const float v = acc[n * PAD + d];
        ob[(long)n * DIN + d] = v > 0.f ? v : expm1f(v);   // elu
    }
}

// ---------------------------------------------------------------- launch
extern "C" void kernel_launch(void* const* d_in, const int* in_sizes, int n_in,
                              void* d_out, int out_size, void* d_ws, size_t ws_size,
                              hipStream_t stream) {
    const float* x     = (const float*)d_in[0];
    const int* eidx    = (const int*)d_in[1];
    const float* eattr = (const float*)d_in[2];
    /* d_in[3] node_mask: unused by the reference forward */
    const void* emraw  = d_in[4];
    const float* W     = (const float*)d_in[5];
    const float* a     = (const float*)d_in[6];
    float* out = (float*)d_out;

    char* ws = (char*)d_ws;
    int* flag            = (int*)(ws + WS_FLAG_OFF);
    unsigned char* mask8 = (unsigned char*)(ws + WS_MASK_OFF);
    float* alpha         = (float*)(ws + WS_ALPHA_OFF);
    float* h             = out;   // scratch aliasing the output buffer
    const bool fused     = (ws_size >= (size_t)WS_NEEDED);
    float* pq            = fused ? (float*)(ws + WS_PQ_OFF) : nullptr;
    float* pt            = fused ? (float*)(ws + WS_PT_OFF) : nullptr;
    unsigned short* wthi = (unsigned short*)(ws + WS_WTHI_OFF);
    unsigned short* wtlo = (unsigned short*)(ws + WS_WTLO_OFF);

    detect_mask_kernel<<<1, 64, 0, stream>>>((const unsigned int*)emraw, flag);
    mask_canon_kernel<<<NMASK / 256, 256, 0, stream>>>(
        (const int*)emraw, (const unsigned char*)emraw, flag, mask8);

    const int M_BLOCKS = MROWS / 128;        // 2056
    if (fused) {
        wprep_kernel<<<1, 256, 0, stream>>>(W, wthi, wtlo);
        mfma_gemm_kernel<<<M_BLOCKS, 256, 0, stream>>>(x, wthi, wtlo, a, h, pq, pt);
        alpha2_kernel<<<BB * SS, 256, 0, stream>>>(pq, pt, eidx, eattr, mask8, a, alpha);
    } else {
        gemm_kernel<<<M_BLOCKS, 256, 0, stream>>>(x, W, h);
        alpha_kernel<<<BB * SS, 256, 0, stream>>>(h, eidx, eattr, mask8, a, alpha);
    }
    agg_kernel<<<dim3(BB * SS, 8), 512, 0, stream>>>(h, eidx, mask8, alpha, out);
}